// Round 2
// baseline (519.310 us; speedup 1.0000x reference)
//
#include <hip/hip_runtime.h>
#include <hip/hip_bf16.h>
#include <stdint.h>
#include <stddef.h>

#define Bn 128
#define Sn 1000
#define SP 1024
#define Hn 256

typedef __bf16 bf16;
typedef __bf16 bf16x8 __attribute__((ext_vector_type(8)));
typedef __bf16 bf16x4 __attribute__((ext_vector_type(4)));
typedef float  f32x16 __attribute__((ext_vector_type(16)));

__device__ __forceinline__ float fast_tanh(float x){
  return 1.0f - 2.0f / (__expf(2.0f * x) + 1.0f);
}
__device__ __forceinline__ float fast_sigmoid(float x){
  return 1.0f / (1.0f + __expf(-x));
}

// ---------------------------------------------------------------------------
// K0w: pack W2 (768x256 bf16, MFMA-fragment-major) and transpose vectors.
// W2 layout: [hb(12)][kt(8)][c(2)][ks(2)][lh(2)][l31(32)][e(8)]
//   hb = p*4+w ; row r = p*256 + w*64 + c*32 + l31 ; k = kt*32+ks*16+lh*8+e
// Each (hb,kt,c,ks) fragment is a contiguous 1KB -> coalesced dwordx4/wave.
__global__ void k0w(const float* __restrict__ We, const float* __restrict__ Wt,
                    const float* __restrict__ Wp, bf16* __restrict__ W2,
                    const float* __restrict__ dec, const float* __restrict__ lhh,
                    const float* __restrict__ tgt, const float* __restrict__ se,
                    float* __restrict__ xT, float* __restrict__ hT,
                    float* __restrict__ tT, float* __restrict__ sT){
  int blk = blockIdx.x, t = threadIdx.x;
  if (blk < 768){
    int tt = blk*256 + t;
    int e   = tt & 7;
    int l31 = (tt>>3) & 31;
    int lh2 = (tt>>8) & 1;
    int ks  = (tt>>9) & 1;
    int c   = (tt>>10) & 1;
    int kt  = (tt>>11) & 7;
    int hb  = tt >> 14;
    int r = (hb>>2)*256 + (hb&3)*64 + c*32 + l31;
    int k = kt*32 + ks*16 + lh2*8 + e;
    float val;
    if (r < 256)       val = We[r*512 + k];
    else if (r < 512)  val = Wt[(r-256)*512 + k];
    else               val = Wp[(r-512)*768 + k];
    W2[tt] = (bf16)val;
  } else {
    int idx = blk - 768;
    int a = idx >> 7, bb = idx & 127;
    const float* src = (a==0) ? dec : (a==1) ? lhh : (a==2) ? tgt : se;
    float* dst       = (a==0) ? xT  : (a==1) ? hT  : (a==2) ? tT  : sT;
    dst[t*128 + bb] = src[bb*256 + t];
  }
}

// ---------------------------------------------------------------------------
// K1a: fused GRU. grid 64 x 512 (group of 128 b-lanes per h).
__global__ __launch_bounds__(512) void k1a_gru(
    const float* __restrict__ xT, const float* __restrict__ hT,
    const float* __restrict__ Wih, const float* __restrict__ Whh,
    const float* __restrict__ bih, const float* __restrict__ bhh,
    float* __restrict__ out_hh, float* __restrict__ hnT){
  int t = threadIdx.x;
  int g = t >> 7, b = t & 127;
  int h = blockIdx.x*4 + g;
  const float4* wir = (const float4*)(Wih + (size_t)h*256);
  const float4* wiz = (const float4*)(Wih + (size_t)(256+h)*256);
  const float4* wig = (const float4*)(Wih + (size_t)(512+h)*256);
  const float4* whr = (const float4*)(Whh + (size_t)h*256);
  const float4* whz = (const float4*)(Whh + (size_t)(256+h)*256);
  const float4* whg = (const float4*)(Whh + (size_t)(512+h)*256);
  float air=0.f, aiz=0.f, aig=0.f, ahr=0.f, ahz=0.f, ahg=0.f;
  #pragma unroll 2
  for (int kq=0; kq<64; kq++){
    float4 vir = wir[kq], viz = wiz[kq], vig = wig[kq];
    float4 vhr = whr[kq], vhz = whz[kq], vhg = whg[kq];
    #pragma unroll
    for (int e=0;e<4;e++){
      int k = kq*4 + e;
      float xv = xT[k*128 + b];
      float hv = hT[k*128 + b];
      air += (&vir.x)[e]*xv; aiz += (&viz.x)[e]*xv; aig += (&vig.x)[e]*xv;
      ahr += (&vhr.x)[e]*hv; ahz += (&vhz.x)[e]*hv; ahg += (&vhg.x)[e]*hv;
    }
  }
  air += bih[h];      ahr += bhh[h];
  aiz += bih[256+h];  ahz += bhh[256+h];
  aig += bih[512+h];  ahg += bhh[512+h];
  float r = fast_sigmoid(air + ahr);
  float z = fast_sigmoid(aiz + ahz);
  float n = fast_tanh(aig + r*ahg);
  float hprev = hT[h*128 + b];
  float hnew = (1.f - z)*n + z*hprev;
  out_hh[b*256 + h] = hnew;
  hnT[h*128 + b] = hnew;
}

// ---------------------------------------------------------------------------
// K1c: d_enc/d_tgt/c3 dots. grid 192 x 512.
__global__ __launch_bounds__(512) void k1c_dots(
    const float* __restrict__ hnT, const float* __restrict__ tT,
    const float* __restrict__ sT,
    const float* __restrict__ We, const float* __restrict__ Wt,
    const float* __restrict__ Wp,
    float* __restrict__ dEnc, float* __restrict__ dTgt, float* __restrict__ c3){
  int t = threadIdx.x;
  int g = t >> 7, b = t & 127;
  int vr = blockIdx.x*4 + g;
  int var = vr >> 8, h = vr & 255;
  const float* wrow; const float* X; float* dst;
  if (var == 0)      { wrow = We + (size_t)h*512 + 256; X = hnT; dst = dEnc; }
  else if (var == 1) { wrow = Wt + (size_t)h*512 + 256; X = tT;  dst = dTgt; }
  else               { wrow = Wp + (size_t)h*768 + 512; X = sT;  dst = c3; }
  const float4* w4 = (const float4*)wrow;
  float acc = 0.f;
  #pragma unroll 2
  for (int kq=0; kq<64; kq++){
    float4 wv = w4[kq];
    #pragma unroll
    for (int e=0;e<4;e++)
      acc += (&wv.x)[e] * X[(kq*4+e)*128 + b];
  }
  dst[b*256 + h] = acc;
}

// ---------------------------------------------------------------------------
// K2: fused GEMM, 32x32x16 MFMA, operand-swapped (D[h][s]).
// Grid (16 st, 128 b) x 256 thr (4 waves, N-split). A (stat fp32->bf16)
// staged ONCE to LDS (32KB, XOR-swizzled, reg-staged). W streamed
// global->registers from fragment-major W2 (coalesced 1KB loads, 2-chunk
// deep double buffer). ZERO __syncthreads in the 24-chunk K-loop: no
// vmcnt(0) drains, W prefetch latency hidden under ~2 chunks of MFMA.
// Per chunk/wave: 4 ds_read_b128 (A) + 4 global dwordx4 (W) + 8 MFMA.
__global__ __launch_bounds__(256, 2) void k2_gemm(
    const float* __restrict__ stat, const bf16* __restrict__ W2,
    const float* __restrict__ dEnc, const float* __restrict__ dTgt,
    const float* __restrict__ vEnc, const float* __restrict__ vTgt,
    float* __restrict__ scE, float* __restrict__ scT, bf16* __restrict__ Aptr){
  __shared__ __align__(16) bf16 As[64*256];   // 32 KB
  __shared__ float scr[2][4][64];             // 2 KB score scratch
  int tid = threadIdx.x, w = tid>>6, l = tid&63;
  int l31 = l&31, lh = l>>5;
  int st = blockIdx.x, b = blockIdx.y;

  // ---- A stage (once): thread (am=tid>>2, agk=tid&3), 8 granule-pairs each
  {
    int am = tid>>2, agk = tid&3;
    bool aValid = (st*64 + am) < Sn;
    const float4* aSrc4 = (const float4*)(stat + ((size_t)b*Sn + st*64 + am)*Hn);
    #pragma unroll
    for (int i=0;i<8;i++){
      int G = i*4 + agk;
      float4 f0 = make_float4(0.f,0.f,0.f,0.f), f1 = f0;
      if (aValid){ f0 = aSrc4[G*2]; f1 = aSrc4[G*2+1]; }
      bf16x8 v;
      v[0]=(bf16)f0.x; v[1]=(bf16)f0.y; v[2]=(bf16)f0.z; v[3]=(bf16)f0.w;
      v[4]=(bf16)f1.x; v[5]=(bf16)f1.y; v[6]=(bf16)f1.z; v[7]=(bf16)f1.w;
      *(bf16x8*)&As[am*256 + ((G ^ (am&7))<<3)] = v;
    }
  }
  __syncthreads();

#define WLOAD(dst, it) { \
  const bf16* wp_ = W2 + ((size_t)(((it)>>3)*4 + w)*8 + (size_t)((it)&7))*2048 + l*8; \
  dst[0] = *(const bf16x8*)(wp_); \
  dst[1] = *(const bf16x8*)(wp_ + 512); \
  dst[2] = *(const bf16x8*)(wp_ + 1024); \
  dst[3] = *(const bf16x8*)(wp_ + 1536); }

#define CHUNK(it, wf) { \
  _Pragma("unroll") \
  for (int ks=0; ks<2; ks++){ \
    int G_ = ((it)&7)*4 + ks*2 + lh; \
    int sa_ = (G_ ^ (l31&7))<<3; \
    bf16x8 af0 = *(const bf16x8*)&As[l31*256 + sa_]; \
    bf16x8 af1 = *(const bf16x8*)&As[(32+l31)*256 + sa_]; \
    acc[0][0] = __builtin_amdgcn_mfma_f32_32x32x16_bf16(wf[ks],   af0, acc[0][0], 0,0,0); \
    acc[1][0] = __builtin_amdgcn_mfma_f32_32x32x16_bf16(wf[ks],   af1, acc[1][0], 0,0,0); \
    acc[0][1] = __builtin_amdgcn_mfma_f32_32x32x16_bf16(wf[2+ks], af0, acc[0][1], 0,0,0); \
    acc[1][1] = __builtin_amdgcn_mfma_f32_32x32x16_bf16(wf[2+ks], af1, acc[1][1], 0,0,0); \
  } }

  bf16x8 wA[4], wB[4];
  WLOAD(wA, 0);
  WLOAD(wB, 1);

  float scp0[2] = {0.f,0.f}, scp1[2] = {0.f,0.f};
  f32x16 acc[2][2];

  #pragma unroll
  for (int p=0; p<3; p++){
    #pragma unroll
    for (int a=0;a<2;a++)
      #pragma unroll
      for (int c=0;c<2;c++)
        #pragma unroll
        for (int r=0;r<16;r++) acc[a][c][r] = 0.f;

    #pragma unroll
    for (int kq=0; kq<4; kq++){
      int it = p*8 + kq*2;
      CHUNK(it, wA);
      if (it+2 < 24) WLOAD(wA, it+2);
      CHUNK(it+1, wB);
      if (it+3 < 24) WLOAD(wB, it+3);
    }

    if (p < 2){
      // in-register score partials: h = w*64 + c*32 + (r&3)+8*(r>>2)+4*lh,
      // s = a*32 + l31.
      const float* vv = p ? vTgt : vEnc;
      const float* db = (p ? dTgt : dEnc) + b*256;
      float s0 = 0.f, s1 = 0.f;
      #pragma unroll
      for (int c=0;c<2;c++){
        int nb = w*64 + c*32 + 4*lh;
        #pragma unroll
        for (int r=0;r<16;r++){
          int n = nb + (r&3) + 8*(r>>2);
          float vdv = vv[n], ddv = db[n];
          s0 += vdv * fast_tanh(acc[0][c][r] + ddv);
          s1 += vdv * fast_tanh(acc[1][c][r] + ddv);
        }
      }
      scp0[p] = s0; scp1[p] = s1;
    }
  }

  // ---- epilogue: transpose ptr-acc into As (s-row-major, swizzled slots)
  __syncthreads();   // all waves done reading As
  #pragma unroll
  for (int a=0;a<2;a++){
    int m = a*32 + l31;
    #pragma unroll
    for (int c=0;c<2;c++){
      int g0 = w*8 + c*4 + lh*2;
      bf16x8 lo, hi;
      #pragma unroll
      for (int r=0;r<8;r++){ lo[r] = (bf16)acc[a][c][r]; hi[r] = (bf16)acc[a][c][8+r]; }
      *(bf16x8*)&As[m*256 + (( g0    ^ (m&7))<<3)] = lo;
      *(bf16x8*)&As[m*256 + (((g0+1) ^ (m&7))<<3)] = hi;
    }
  }
  #pragma unroll
  for (int p2=0;p2<2;p2++){
    float v0 = scp0[p2] + __shfl_xor(scp0[p2], 32);
    float v1 = scp1[p2] + __shfl_xor(scp1[p2], 32);
    if (lh == 0){
      scr[p2][w][l31]      = v0;
      scr[p2][w][32 + l31] = v1;
    }
  }
  __syncthreads();
  if (tid < 128){
    int pp = tid>>6, m = tid&63;
    float s = scr[pp][0][m] + scr[pp][1][m] + scr[pp][2][m] + scr[pp][3][m];
    (pp ? scT : scE)[b*SP + st*64 + m] = s;
  }
  // coalesced Aptr store: thread t -> row m = t>>2, quarter part = t&3 (128 B)
  {
    int m = tid>>2, part = tid&3;
    bf16* dst = Aptr + ((size_t)(b*1024 + st*64 + m))*256 + part*64;
    #pragma unroll
    for (int i=0;i<8;i++){
      int g = (part*8 + i) ^ (m&7);
      *(bf16x8*)(dst + i*8) = *(const bf16x8*)&As[m*256 + (g<<3)];
    }
  }
#undef WLOAD
#undef CHUNK
}

// ---------------------------------------------------------------------------
// K3: softmax (full S, both branches) + context over 500 rows, float4 cols.
// grid (128 b, 2 sg) x 1024. Partials atomicAdd into ctxG [var][b][h] (zeroed).
__global__ __launch_bounds__(1024) void k3_ctx(
    const float* __restrict__ scE, const float* __restrict__ scT,
    const float* __restrict__ stat, float* __restrict__ ctxG){
  __shared__ float attE[500], attT[500];
  __shared__ float redE[16], redT[16];
  __shared__ float4 pe4[16][64], pt4[16][64];
  int b = blockIdx.x, sg = blockIdx.y, t = threadIdx.x;
  int wid = t>>6, ln = t&63;

  float vE = (t < Sn) ? scE[b*SP + t] : -1e30f;
  float vT = (t < Sn) ? scT[b*SP + t] : -1e30f;
  float mE = vE, mT = vT;
  #pragma unroll
  for (int o=1;o<64;o<<=1){ mE=fmaxf(mE,__shfl_xor(mE,o)); mT=fmaxf(mT,__shfl_xor(mT,o)); }
  if (ln==0){ redE[wid]=mE; redT[wid]=mT; }
  __syncthreads();
  float ME=-1e30f, MT=-1e30f;
  #pragma unroll
  for (int i=0;i<16;i++){ ME=fmaxf(ME,redE[i]); MT=fmaxf(MT,redT[i]); }
  __syncthreads();
  float eE = (t < Sn) ? __expf(vE-ME) : 0.f;
  float eT = (t < Sn) ? __expf(vT-MT) : 0.f;
  float sE=eE, sT=eT;
  #pragma unroll
  for (int o=1;o<64;o<<=1){ sE+=__shfl_xor(sE,o); sT+=__shfl_xor(sT,o); }
  if (ln==0){ redE[wid]=sE; redT[wid]=sT; }
  __syncthreads();
  float SE=0.f, ST=0.f;
  #pragma unroll
  for (int i=0;i<16;i++){ SE+=redE[i]; ST+=redT[i]; }
  float invE = 1.f/SE, invT = 1.f/ST;
  if (t < 500){
    int s = sg*500 + t;
    attE[t] = __expf(scE[b*SP+s]-ME)*invE;
    attT[t] = __expf(scT[b*SP+s]-MT)*invT;
  }
  __syncthreads();

  int h4 = t & 63, rg = t >> 6;
  float4 aE = make_float4(0.f,0.f,0.f,0.f), aT = aE;
  int nrows = (rg == 15) ? 20 : 32;
  const float4* base = (const float4*)(stat + ((size_t)(b*Sn + sg*500 + rg*32))*Hn) + h4;
  #pragma unroll 4
  for (int i=0;i<nrows;i++){
    float4 f = base[(size_t)i*64];
    float wE = attE[rg*32 + i], wT = attT[rg*32 + i];
    aE.x += wE*f.x; aE.y += wE*f.y; aE.z += wE*f.z; aE.w += wE*f.w;
    aT.x += wT*f.x; aT.y += wT*f.y; aT.z += wT*f.z; aT.w += wT*f.w;
  }
  pe4[rg][h4] = aE; pt4[rg][h4] = aT;
  __syncthreads();
  if (t < 64){
    float4 s = make_float4(0.f,0.f,0.f,0.f);
    #pragma unroll
    for (int i=0;i<16;i++){
      float4 p = pe4[i][t];
      s.x+=p.x; s.y+=p.y; s.z+=p.z; s.w+=p.w;
    }
    atomicAdd(&ctxG[b*256 + t*4 + 0], s.x);
    atomicAdd(&ctxG[b*256 + t*4 + 1], s.y);
    atomicAdd(&ctxG[b*256 + t*4 + 2], s.z);
    atomicAdd(&ctxG[b*256 + t*4 + 3], s.w);
  } else if (t < 128){
    int h = t - 64;
    float4 s = make_float4(0.f,0.f,0.f,0.f);
    #pragma unroll
    for (int i=0;i<16;i++){
      float4 p = pt4[i][h];
      s.x+=p.x; s.y+=p.y; s.z+=p.z; s.w+=p.w;
    }
    atomicAdd(&ctxG[32768 + b*256 + h*4 + 0], s.x);
    atomicAdd(&ctxG[32768 + b*256 + h*4 + 1], s.y);
    atomicAdd(&ctxG[32768 + b*256 + h*4 + 2], s.z);
    atomicAdd(&ctxG[32768 + b*256 + h*4 + 3], s.w);
  }
}

// ---------------------------------------------------------------------------
// K3c: c2 = Wptr[:,H:2H]@ctx + c3. grid 128 (b) x 512 (2 var x 256 h).
__global__ __launch_bounds__(512) void k3c_c2(
    const float* __restrict__ ctxG, const float* __restrict__ Wp,
    const float* __restrict__ c3,
    float* __restrict__ cE, float* __restrict__ cT){
  __shared__ __align__(16) float ctxL[512];
  int b = blockIdx.x, t = threadIdx.x;
  ctxL[t] = ctxG[(t>>8)*32768 + b*256 + (t&255)];
  __syncthreads();
  int var = t >> 8, h = t & 255;
  const float4* w4 = (const float4*)(Wp + (size_t)h*768 + 256);
  const float4* cv = (const float4*)(&ctxL[var*256]);
  float acc = 0.f;
  #pragma unroll 4
  for (int k=0;k<64;k++){
    float4 wv = w4[k], xv = cv[k];
    acc += wv.x*xv.x + wv.y*xv.y + wv.z*xv.z + wv.w*xv.w;
  }
  (var ? cT : cE)[b*256 + h] = acc + c3[b*256 + h];
}

// ---------------------------------------------------------------------------
// K4: final reduction. Aptr is s-row-major (256 bf16 per s, slot-permuted).
// grid (16 st, 128 b) x 256: lane-quad per s-row; no LDS, no atomics.
__global__ __launch_bounds__(256) void k4_final(
    const bf16* __restrict__ Aptr, const float* __restrict__ cE,
    const float* __restrict__ cT, const float* __restrict__ vp,
    float* __restrict__ out){
  int t = threadIdx.x;
  int st = blockIdx.x, b = blockIdx.y;
  int m = t>>2, part = t&3;
  const bf16* src = Aptr + ((size_t)(b*1024 + st*64 + m))*256 + part*64;
  const float* vpb = vp + part*64;
  const float* ceb = cE + b*256 + part*64;
  const float* ctb = cT + b*256 + part*64;
  float pe = 0.f, pt = 0.f;
  #pragma unroll
  for (int i=0;i<8;i++){
    bf16x8 av = *(const bf16x8*)(src + i*8);
    int bi = ((i>>2)<<5) + (((i>>1)&1)<<2) + ((i&1)<<4);
    float4 v0 = *(const float4*)(vpb + bi), v1 = *(const float4*)(vpb + bi + 8);
    float4 e0 = *(const float4*)(ceb + bi), e1 = *(const float4*)(ceb + bi + 8);
    float4 t0 = *(const float4*)(ctb + bi), t1 = *(const float4*)(ctb + bi + 8);
    #pragma unroll
    for (int j=0;j<4;j++){
      float a = (float)av[j];
      pe += (&v0.x)[j] * fast_tanh(a + (&e0.x)[j]);
      pt += (&v0.x)[j] * fast_tanh(a + (&t0.x)[j]);
    }
    #pragma unroll
    for (int j=0;j<4;j++){
      float a = (float)av[4+j];
      pe += (&v1.x)[j] * fast_tanh(a + (&e1.x)[j]);
      pt += (&v1.x)[j] * fast_tanh(a + (&t1.x)[j]);
    }
  }
  pe += __shfl_xor(pe,1); pe += __shfl_xor(pe,2);
  pt += __shfl_xor(pt,1); pt += __shfl_xor(pt,2);
  int s = st*64 + m;
  if (part==0 && s < Sn) out[(size_t)b*Sn + s] = 5.0f*pe + pt;
}

// ---------------------------------------------------------------------------
extern "C" void kernel_launch(void* const* d_in, const int* in_sizes, int n_in,
                              void* d_out, int out_size, void* d_ws, size_t ws_size,
                              hipStream_t stream){
  const float* stat = (const float*)d_in[0];
  const float* se   = (const float*)d_in[1];
  const float* dec  = (const float*)d_in[2];
  const float* tgt  = (const float*)d_in[3];
  const float* lhh  = (const float*)d_in[4];
  const float* Wih  = (const float*)d_in[5];
  const float* Whh  = (const float*)d_in[6];
  const float* bih  = (const float*)d_in[7];
  const float* bhh  = (const float*)d_in[8];
  const float* vEnc = (const float*)d_in[9];
  const float* WEnc = (const float*)d_in[10];
  const float* vTgt = (const float*)d_in[11];
  const float* WTgt = (const float*)d_in[12];
  const float* vPtr = (const float*)d_in[13];
  const float* WPtr = (const float*)d_in[14];
  float* out = (float*)d_out;

  char* wsp = (char*)d_ws;
  bf16*  Aptr = (bf16*)(wsp);                  // 67,108,864
  bf16*  W2   = (bf16*)(wsp + 67108864);       // 393,216
  float* xT   = (float*)(wsp + 67502080);      // 131,072
  float* hT   = (float*)(wsp + 67633152);      // 131,072
  float* tT   = (float*)(wsp + 67764224);      // 131,072
  float* sT   = (float*)(wsp + 67895296);      // 131,072
  float* hnT  = (float*)(wsp + 68026368);      // 131,072
  float* scE  = (float*)(wsp + 68157440);      // 524,288
  float* scT  = (float*)(wsp + 68681728);      // 524,288
  float* dEnc = (float*)(wsp + 69206016);      // 131,072
  float* dTgt = (float*)(wsp + 69337088);      // 131,072
  float* c3   = (float*)(wsp + 69468160);      // 131,072
  float* cE   = (float*)(wsp + 69599232);      // 131,072
  float* cT   = (float*)(wsp + 69730304);      // 131,072
  float* ctxG = (float*)(wsp + 69861376);      // 262,144 -> end 70,123,520

  hipMemsetAsync(ctxG, 0, 262144, stream);
  hipLaunchKernelGGL(k0w, dim3(1280), dim3(256), 0, stream,
                     WEnc, WTgt, WPtr, W2, dec, lhh, tgt, se, xT, hT, tT, sT);
  hipLaunchKernelGGL(k1a_gru, dim3(64), dim3(512), 0, stream,
                     xT, hT, Wih, Whh, bih, bhh, out + Bn*Sn, hnT);
  hipLaunchKernelGGL(k1c_dots, dim3(192), dim3(512), 0, stream,
                     hnT, tT, sT, WEnc, WTgt, WPtr, dEnc, dTgt, c3);
  hipLaunchKernelGGL(k2_gemm, dim3(16, 128), dim3(256), 0, stream,
                     stat, W2, dEnc, dTgt, vEnc, vTgt, scE, scT, Aptr);
  hipLaunchKernelGGL(k3_ctx, dim3(128, 2), dim3(1024), 0, stream,
                     scE, scT, stat, ctxG);
  hipLaunchKernelGGL(k3c_c2, dim3(128), dim3(512), 0, stream,
                     ctxG, WPtr, c3, cE, cT);
  hipLaunchKernelGGL(k4_final, dim3(16, 128), dim3(256), 0, stream,
                     Aptr, cE, cT, vPtr, out);
}

// Round 3
// 455.246 us; speedup vs baseline: 1.1407x; 1.1407x over previous
//
#include <hip/hip_runtime.h>
#include <hip/hip_bf16.h>
#include <stdint.h>
#include <stddef.h>

#define Bn 128
#define Sn 1000
#define SP 1024
#define Hn 256

typedef __bf16 bf16;
typedef __bf16 bf16x8 __attribute__((ext_vector_type(8)));
typedef __bf16 bf16x4 __attribute__((ext_vector_type(4)));
typedef float  f32x16 __attribute__((ext_vector_type(16)));

typedef __attribute__((address_space(1))) const unsigned int* gas1;
typedef __attribute__((address_space(3))) unsigned int* las3;

__device__ __forceinline__ float fast_tanh(float x){
  return 1.0f - 2.0f / (__expf(2.0f * x) + 1.0f);
}
__device__ __forceinline__ float fast_sigmoid(float x){
  return 1.0f / (1.0f + __expf(-x));
}

// ---------------------------------------------------------------------------
// K0w: pack Wc (768x256 bf16, plain row-major) and transpose vectors to [k][b].
__global__ void k0w(const float* __restrict__ We, const float* __restrict__ Wt,
                    const float* __restrict__ Wp, bf16* __restrict__ Wcb,
                    const float* __restrict__ dec, const float* __restrict__ lhh,
                    const float* __restrict__ tgt, const float* __restrict__ se,
                    float* __restrict__ xT, float* __restrict__ hT,
                    float* __restrict__ tT, float* __restrict__ sT){
  int blk = blockIdx.x, t = threadIdx.x;
  if (blk < 768){
    int tt = blk*256 + t;
    int r = tt >> 8, c = tt & 255;
    float val;
    if (r < 256)       val = We[r*512 + c];
    else if (r < 512)  val = Wt[(r-256)*512 + c];
    else               val = Wp[(r-512)*768 + c];
    Wcb[tt] = (bf16)val;
  } else {
    int idx = blk - 768;
    int a = idx >> 7, bb = idx & 127;
    const float* src = (a==0) ? dec : (a==1) ? lhh : (a==2) ? tgt : se;
    float* dst       = (a==0) ? xT  : (a==1) ? hT  : (a==2) ? tT  : sT;
    dst[t*128 + bb] = src[bb*256 + t];
  }
}

// ---------------------------------------------------------------------------
// K1a: fused GRU. grid 64 x 512 (group of 128 b-lanes per h).
__global__ __launch_bounds__(512) void k1a_gru(
    const float* __restrict__ xT, const float* __restrict__ hT,
    const float* __restrict__ Wih, const float* __restrict__ Whh,
    const float* __restrict__ bih, const float* __restrict__ bhh,
    float* __restrict__ out_hh, float* __restrict__ hnT){
  int t = threadIdx.x;
  int g = t >> 7, b = t & 127;
  int h = blockIdx.x*4 + g;
  const float4* wir = (const float4*)(Wih + (size_t)h*256);
  const float4* wiz = (const float4*)(Wih + (size_t)(256+h)*256);
  const float4* wig = (const float4*)(Wih + (size_t)(512+h)*256);
  const float4* whr = (const float4*)(Whh + (size_t)h*256);
  const float4* whz = (const float4*)(Whh + (size_t)(256+h)*256);
  const float4* whg = (const float4*)(Whh + (size_t)(512+h)*256);
  float air=0.f, aiz=0.f, aig=0.f, ahr=0.f, ahz=0.f, ahg=0.f;
  #pragma unroll 2
  for (int kq=0; kq<64; kq++){
    float4 vir = wir[kq], viz = wiz[kq], vig = wig[kq];
    float4 vhr = whr[kq], vhz = whz[kq], vhg = whg[kq];
    #pragma unroll
    for (int e=0;e<4;e++){
      int k = kq*4 + e;
      float xv = xT[k*128 + b];
      float hv = hT[k*128 + b];
      air += (&vir.x)[e]*xv; aiz += (&viz.x)[e]*xv; aig += (&vig.x)[e]*xv;
      ahr += (&vhr.x)[e]*hv; ahz += (&vhz.x)[e]*hv; ahg += (&vhg.x)[e]*hv;
    }
  }
  air += bih[h];      ahr += bhh[h];
  aiz += bih[256+h];  ahz += bhh[256+h];
  aig += bih[512+h];  ahg += bhh[512+h];
  float r = fast_sigmoid(air + ahr);
  float z = fast_sigmoid(aiz + ahz);
  float n = fast_tanh(aig + r*ahg);
  float hprev = hT[h*128 + b];
  float hnew = (1.f - z)*n + z*hprev;
  out_hh[b*256 + h] = hnew;
  hnT[h*128 + b] = hnew;
}

// ---------------------------------------------------------------------------
// K1c: d_enc/d_tgt/c3 dots. grid 192 x 512.
__global__ __launch_bounds__(512) void k1c_dots(
    const float* __restrict__ hnT, const float* __restrict__ tT,
    const float* __restrict__ sT,
    const float* __restrict__ We, const float* __restrict__ Wt,
    const float* __restrict__ Wp,
    float* __restrict__ dEnc, float* __restrict__ dTgt, float* __restrict__ c3){
  int t = threadIdx.x;
  int g = t >> 7, b = t & 127;
  int vr = blockIdx.x*4 + g;
  int var = vr >> 8, h = vr & 255;
  const float* wrow; const float* X; float* dst;
  if (var == 0)      { wrow = We + (size_t)h*512 + 256; X = hnT; dst = dEnc; }
  else if (var == 1) { wrow = Wt + (size_t)h*512 + 256; X = tT;  dst = dTgt; }
  else               { wrow = Wp + (size_t)h*768 + 512; X = sT;  dst = c3; }
  const float4* w4 = (const float4*)wrow;
  float acc = 0.f;
  #pragma unroll 2
  for (int kq=0; kq<64; kq++){
    float4 wv = w4[kq];
    #pragma unroll
    for (int e=0;e<4;e++)
      acc += (&wv.x)[e] * X[(kq*4+e)*128 + b];
  }
  dst[b*256 + h] = acc;
}

// ---------------------------------------------------------------------------
// K2: fused GEMM, 32x32x16 MFMA, operand-swapped (D[h][s]).
// Grid (16 st, 128 b) x 256 thr (4 waves, N-split). A staged once to LDS
// (32 KB, XOR-swizzled). B (Wcb) double-buffered in LDS via pre-swizzled
// global_load_lds. T3/T4 protocol: counted s_waitcnt vmcnt(4) + raw
// s_barrier — loads waited on were issued one full chunk earlier; NEVER
// vmcnt(0) in the steady-state loop (the round-0/1 killer).
__global__ __launch_bounds__(256, 2) void k2_gemm(
    const float* __restrict__ stat, const bf16* __restrict__ Wcb,
    const float* __restrict__ dEnc, const float* __restrict__ dTgt,
    const float* __restrict__ vEnc, const float* __restrict__ vTgt,
    float* __restrict__ scE, float* __restrict__ scT, bf16* __restrict__ Aptr){
  __shared__ __align__(16) bf16 As[64*256];     // 32 KB
  __shared__ __align__(16) bf16 Bs[2][256*32];  // 2 x 16 KB
  __shared__ float scr[2][4][64];               // 2 KB
  int tid = threadIdx.x, w = tid>>6, l = tid&63;
  int l31 = l&31, lh = l>>5;
  int st = blockIdx.x, b = blockIdx.y;

  // B-stage lane constants
  int bnb = w*16 + (l>>2);
  int bg  = l&3;

  // ---- A stage (once): thread (am=tid>>2, agk=tid&3), 8 granule-pairs each
  {
    int am = tid>>2, agk = tid&3;
    bool aValid = (st*64 + am) < Sn;
    const float4* aSrc4 = (const float4*)(stat + ((size_t)b*Sn + st*64 + am)*Hn);
    #pragma unroll
    for (int i=0;i<8;i++){
      int G = i*4 + agk;
      float4 f0 = make_float4(0.f,0.f,0.f,0.f), f1 = f0;
      if (aValid){ f0 = aSrc4[G*2]; f1 = aSrc4[G*2+1]; }
      bf16x8 v;
      v[0]=(bf16)f0.x; v[1]=(bf16)f0.y; v[2]=(bf16)f0.z; v[3]=(bf16)f0.w;
      v[4]=(bf16)f1.x; v[5]=(bf16)f1.y; v[6]=(bf16)f1.z; v[7]=(bf16)f1.w;
      *(bf16x8*)&As[am*256 + ((G ^ (am&7))<<3)] = v;
    }
  }
  __syncthreads();   // As visible to all waves (drains everything; B not yet issued)

#define STAGE(it, buf) { \
  const bf16* wb_ = Wcb + (size_t)((it)>>3)*65536 + ((it)&7)*32; \
  _Pragma("unroll") \
  for (int i_=0;i_<4;i_++){ \
    int n_ = i_*64 + bnb; \
    int g_ = bg ^ ((n_>>1)&3); \
    __builtin_amdgcn_global_load_lds((gas1)(wb_ + (size_t)n_*256 + g_*8), \
        (las3)(&Bs[buf][i_*2048 + w*512]), 16, 0, 0); \
  } }

#define CHUNK(it) { \
  const bf16* bsr_ = &Bs[(it)&1][0]; \
  _Pragma("unroll") \
  for (int ks=0; ks<2; ks++){ \
    int kg_ = ks*2 + lh; \
    int G_ = ((it)&7)*4 + kg_; \
    int sa_ = (G_ ^ (l31&7))<<3; \
    bf16x8 af0 = *(const bf16x8*)&As[l31*256 + sa_]; \
    bf16x8 af1 = *(const bf16x8*)&As[(32+l31)*256 + sa_]; \
    _Pragma("unroll") \
    for (int c_=0;c_<2;c_++){ \
      int n_ = w*64 + c_*32 + l31; \
      bf16x8 wf = *(const bf16x8*)&bsr_[n_*32 + ((kg_ ^ ((n_>>1)&3))<<3)]; \
      acc[0][c_] = __builtin_amdgcn_mfma_f32_32x32x16_bf16(wf, af0, acc[0][c_], 0,0,0); \
      acc[1][c_] = __builtin_amdgcn_mfma_f32_32x32x16_bf16(wf, af1, acc[1][c_], 0,0,0); \
    } \
  } }

  // ---- prologue: stage chunks 0 and 1; wait only for chunk 0 (vmcnt(4))
  STAGE(0, 0);
  STAGE(1, 1);
  __builtin_amdgcn_sched_barrier(0);
  asm volatile("s_waitcnt vmcnt(4)" ::: "memory");
  __builtin_amdgcn_sched_barrier(0);
  __builtin_amdgcn_s_barrier();
  __builtin_amdgcn_sched_barrier(0);

  float scp0[2] = {0.f,0.f}, scp1[2] = {0.f,0.f};
  f32x16 acc[2][2];

  #pragma unroll
  for (int p=0; p<3; p++){
    #pragma unroll
    for (int a=0;a<2;a++)
      #pragma unroll
      for (int c=0;c<2;c++)
        #pragma unroll
        for (int r=0;r<16;r++) acc[a][c][r] = 0.f;

    #pragma unroll
    for (int kt=0; kt<8; kt++){
      int it = p*8 + kt;
      CHUNK(it);
      if (it < 23){
        __builtin_amdgcn_sched_barrier(0);
        __builtin_amdgcn_s_barrier();          // all waves done reading Bs[it&1]
        __builtin_amdgcn_sched_barrier(0);
        if (it < 22){ STAGE(it+2, (it&1)); }   // refill the buffer just freed
        __builtin_amdgcn_sched_barrier(0);
        if (it < 22){ asm volatile("s_waitcnt vmcnt(4)" ::: "memory"); }
        else        { asm volatile("s_waitcnt vmcnt(0)" ::: "memory"); }
        __builtin_amdgcn_sched_barrier(0);
        __builtin_amdgcn_s_barrier();          // everyone's chunk it+1 staged
        __builtin_amdgcn_sched_barrier(0);
      }
    }

    if (p < 2){
      // in-register score partials: h = w*64 + c*32 + (r&3)+8*(r>>2)+4*lh,
      // s = a*32 + l31.
      const float* vv = p ? vTgt : vEnc;
      const float* db = (p ? dTgt : dEnc) + b*256;
      float s0 = 0.f, s1 = 0.f;
      #pragma unroll
      for (int c=0;c<2;c++){
        int nb = w*64 + c*32 + 4*lh;
        #pragma unroll
        for (int r=0;r<16;r++){
          int n = nb + (r&3) + 8*(r>>2);
          float vdv = vv[n], ddv = db[n];
          s0 += vdv * fast_tanh(acc[0][c][r] + ddv);
          s1 += vdv * fast_tanh(acc[1][c][r] + ddv);
        }
      }
      scp0[p] = s0; scp1[p] = s1;
    }
  }

  // ---- epilogue: transpose ptr-acc into As (s-row-major, swizzled slots)
  __syncthreads();   // all waves done reading As
  #pragma unroll
  for (int a=0;a<2;a++){
    int m = a*32 + l31;
    #pragma unroll
    for (int c=0;c<2;c++){
      int g0 = w*8 + c*4 + lh*2;
      bf16x8 lo, hi;
      #pragma unroll
      for (int r=0;r<8;r++){ lo[r] = (bf16)acc[a][c][r]; hi[r] = (bf16)acc[a][c][8+r]; }
      *(bf16x8*)&As[m*256 + (( g0    ^ (m&7))<<3)] = lo;
      *(bf16x8*)&As[m*256 + (((g0+1) ^ (m&7))<<3)] = hi;
    }
  }
  #pragma unroll
  for (int p2=0;p2<2;p2++){
    float v0 = scp0[p2] + __shfl_xor(scp0[p2], 32);
    float v1 = scp1[p2] + __shfl_xor(scp1[p2], 32);
    if (lh == 0){
      scr[p2][w][l31]      = v0;
      scr[p2][w][32 + l31] = v1;
    }
  }
  __syncthreads();
  if (tid < 128){
    int pp = tid>>6, m = tid&63;
    float s = scr[pp][0][m] + scr[pp][1][m] + scr[pp][2][m] + scr[pp][3][m];
    (pp ? scT : scE)[b*SP + st*64 + m] = s;
  }
  // coalesced Aptr store: thread t -> row m = t>>2, quarter part = t&3 (128 B)
  {
    int m = tid>>2, part = tid&3;
    bf16* dst = Aptr + ((size_t)(b*1024 + st*64 + m))*256 + part*64;
    #pragma unroll
    for (int i=0;i<8;i++){
      int g = (part*8 + i) ^ (m&7);
      *(bf16x8*)(dst + i*8) = *(const bf16x8*)&As[m*256 + (g<<3)];
    }
  }
#undef STAGE
#undef CHUNK
}

// ---------------------------------------------------------------------------
// K3: softmax (full S, both branches) + context over 500 rows, float4 cols.
// grid (128 b, 2 sg) x 1024. Partials atomicAdd into ctxG [var][b][h] (zeroed).
__global__ __launch_bounds__(1024) void k3_ctx(
    const float* __restrict__ scE, const float* __restrict__ scT,
    const float* __restrict__ stat, float* __restrict__ ctxG){
  __shared__ float attE[500], attT[500];
  __shared__ float redE[16], redT[16];
  __shared__ float4 pe4[16][64], pt4[16][64];
  int b = blockIdx.x, sg = blockIdx.y, t = threadIdx.x;
  int wid = t>>6, ln = t&63;

  float vE = (t < Sn) ? scE[b*SP + t] : -1e30f;
  float vT = (t < Sn) ? scT[b*SP + t] : -1e30f;
  float mE = vE, mT = vT;
  #pragma unroll
  for (int o=1;o<64;o<<=1){ mE=fmaxf(mE,__shfl_xor(mE,o)); mT=fmaxf(mT,__shfl_xor(mT,o)); }
  if (ln==0){ redE[wid]=mE; redT[wid]=mT; }
  __syncthreads();
  float ME=-1e30f, MT=-1e30f;
  #pragma unroll
  for (int i=0;i<16;i++){ ME=fmaxf(ME,redE[i]); MT=fmaxf(MT,redT[i]); }
  __syncthreads();
  float eE = (t < Sn) ? __expf(vE-ME) : 0.f;
  float eT = (t < Sn) ? __expf(vT-MT) : 0.f;
  float sE=eE, sT=eT;
  #pragma unroll
  for (int o=1;o<64;o<<=1){ sE+=__shfl_xor(sE,o); sT+=__shfl_xor(sT,o); }
  if (ln==0){ redE[wid]=sE; redT[wid]=sT; }
  __syncthreads();
  float SE=0.f, ST=0.f;
  #pragma unroll
  for (int i=0;i<16;i++){ SE+=redE[i]; ST+=redT[i]; }
  float invE = 1.f/SE, invT = 1.f/ST;
  if (t < 500){
    int s = sg*500 + t;
    attE[t] = __expf(scE[b*SP+s]-ME)*invE;
    attT[t] = __expf(scT[b*SP+s]-MT)*invT;
  }
  __syncthreads();

  int h4 = t & 63, rg = t >> 6;
  float4 aE = make_float4(0.f,0.f,0.f,0.f), aT = aE;
  int nrows = (rg == 15) ? 20 : 32;
  const float4* base = (const float4*)(stat + ((size_t)(b*Sn + sg*500 + rg*32))*Hn) + h4;
  #pragma unroll 4
  for (int i=0;i<nrows;i++){
    float4 f = base[(size_t)i*64];
    float wE = attE[rg*32 + i], wT = attT[rg*32 + i];
    aE.x += wE*f.x; aE.y += wE*f.y; aE.z += wE*f.z; aE.w += wE*f.w;
    aT.x += wT*f.x; aT.y += wT*f.y; aT.z += wT*f.z; aT.w += wT*f.w;
  }
  pe4[rg][h4] = aE; pt4[rg][h4] = aT;
  __syncthreads();
  if (t < 64){
    float4 s = make_float4(0.f,0.f,0.f,0.f);
    #pragma unroll
    for (int i=0;i<16;i++){
      float4 p = pe4[i][t];
      s.x+=p.x; s.y+=p.y; s.z+=p.z; s.w+=p.w;
    }
    atomicAdd(&ctxG[b*256 + t*4 + 0], s.x);
    atomicAdd(&ctxG[b*256 + t*4 + 1], s.y);
    atomicAdd(&ctxG[b*256 + t*4 + 2], s.z);
    atomicAdd(&ctxG[b*256 + t*4 + 3], s.w);
  } else if (t < 128){
    int h = t - 64;
    float4 s = make_float4(0.f,0.f,0.f,0.f);
    #pragma unroll
    for (int i=0;i<16;i++){
      float4 p = pt4[i][h];
      s.x+=p.x; s.y+=p.y; s.z+=p.z; s.w+=p.w;
    }
    atomicAdd(&ctxG[32768 + b*256 + h*4 + 0], s.x);
    atomicAdd(&ctxG[32768 + b*256 + h*4 + 1], s.y);
    atomicAdd(&ctxG[32768 + b*256 + h*4 + 2], s.z);
    atomicAdd(&ctxG[32768 + b*256 + h*4 + 3], s.w);
  }
}

// ---------------------------------------------------------------------------
// K3c: c2 = Wptr[:,H:2H]@ctx + c3. grid 128 (b) x 512 (2 var x 256 h).
__global__ __launch_bounds__(512) void k3c_c2(
    const float* __restrict__ ctxG, const float* __restrict__ Wp,
    const float* __restrict__ c3,
    float* __restrict__ cE, float* __restrict__ cT){
  __shared__ __align__(16) float ctxL[512];
  int b = blockIdx.x, t = threadIdx.x;
  ctxL[t] = ctxG[(t>>8)*32768 + b*256 + (t&255)];
  __syncthreads();
  int var = t >> 8, h = t & 255;
  const float4* w4 = (const float4*)(Wp + (size_t)h*768 + 256);
  const float4* cv = (const float4*)(&ctxL[var*256]);
  float acc = 0.f;
  #pragma unroll 4
  for (int k=0;k<64;k++){
    float4 wv = w4[k], xv = cv[k];
    acc += wv.x*xv.x + wv.y*xv.y + wv.z*xv.z + wv.w*xv.w;
  }
  (var ? cT : cE)[b*256 + h] = acc + c3[b*256 + h];
}

// ---------------------------------------------------------------------------
// K4: final reduction. Aptr is s-row-major (256 bf16 per s, slot-permuted).
// grid (16 st, 128 b) x 256: lane-quad per s-row; no LDS, no atomics.
__global__ __launch_bounds__(256) void k4_final(
    const bf16* __restrict__ Aptr, const float* __restrict__ cE,
    const float* __restrict__ cT, const float* __restrict__ vp,
    float* __restrict__ out){
  int t = threadIdx.x;
  int st = blockIdx.x, b = blockIdx.y;
  int m = t>>2, part = t&3;
  const bf16* src = Aptr + ((size_t)(b*1024 + st*64 + m))*256 + part*64;
  const float* vpb = vp + part*64;
  const float* ceb = cE + b*256 + part*64;
  const float* ctb = cT + b*256 + part*64;
  float pe = 0.f, pt = 0.f;
  #pragma unroll
  for (int i=0;i<8;i++){
    bf16x8 av = *(const bf16x8*)(src + i*8);
    int bi = ((i>>2)<<5) + (((i>>1)&1)<<2) + ((i&1)<<4);
    float4 v0 = *(const float4*)(vpb + bi), v1 = *(const float4*)(vpb + bi + 8);
    float4 e0 = *(const float4*)(ceb + bi), e1 = *(const float4*)(ceb + bi + 8);
    float4 t0 = *(const float4*)(ctb + bi), t1 = *(const float4*)(ctb + bi + 8);
    #pragma unroll
    for (int j=0;j<4;j++){
      float a = (float)av[j];
      pe += (&v0.x)[j] * fast_tanh(a + (&e0.x)[j]);
      pt += (&v0.x)[j] * fast_tanh(a + (&t0.x)[j]);
    }
    #pragma unroll
    for (int j=0;j<4;j++){
      float a = (float)av[4+j];
      pe += (&v1.x)[j] * fast_tanh(a + (&e1.x)[j]);
      pt += (&v1.x)[j] * fast_tanh(a + (&t1.x)[j]);
    }
  }
  pe += __shfl_xor(pe,1); pe += __shfl_xor(pe,2);
  pt += __shfl_xor(pt,1); pt += __shfl_xor(pt,2);
  int s = st*64 + m;
  if (part==0 && s < Sn) out[(size_t)b*Sn + s] = 5.0f*pe + pt;
}

// ---------------------------------------------------------------------------
extern "C" void kernel_launch(void* const* d_in, const int* in_sizes, int n_in,
                              void* d_out, int out_size, void* d_ws, size_t ws_size,
                              hipStream_t stream){
  const float* stat = (const float*)d_in[0];
  const float* se   = (const float*)d_in[1];
  const float* dec  = (const float*)d_in[2];
  const float* tgt  = (const float*)d_in[3];
  const float* lhh  = (const float*)d_in[4];
  const float* Wih  = (const float*)d_in[5];
  const float* Whh  = (const float*)d_in[6];
  const float* bih  = (const float*)d_in[7];
  const float* bhh  = (const float*)d_in[8];
  const float* vEnc = (const float*)d_in[9];
  const float* WEnc = (const float*)d_in[10];
  const float* vTgt = (const float*)d_in[11];
  const float* WTgt = (const float*)d_in[12];
  const float* vPtr = (const float*)d_in[13];
  const float* WPtr = (const float*)d_in[14];
  float* out = (float*)d_out;

  char* wsp = (char*)d_ws;
  bf16*  Aptr = (bf16*)(wsp);                  // 67,108,864
  bf16*  Wcb  = (bf16*)(wsp + 67108864);       // 393,216
  float* xT   = (float*)(wsp + 67502080);      // 131,072
  float* hT   = (float*)(wsp + 67633152);      // 131,072
  float* tT   = (float*)(wsp + 67764224);      // 131,072
  float* sT   = (float*)(wsp + 67895296);      // 131,072
  float* hnT  = (float*)(wsp + 68026368);      // 131,072
  float* scE  = (float*)(wsp + 68157440);      // 524,288
  float* scT  = (float*)(wsp + 68681728);      // 524,288
  float* dEnc = (float*)(wsp + 69206016);      // 131,072
  float* dTgt = (float*)(wsp + 69337088);      // 131,072
  float* c3   = (float*)(wsp + 69468160);      // 131,072
  float* cE   = (float*)(wsp + 69599232);      // 131,072
  float* cT   = (float*)(wsp + 69730304);      // 131,072
  float* ctxG = (float*)(wsp + 69861376);      // 262,144 -> end 70,123,520

  hipMemsetAsync(ctxG, 0, 262144, stream);
  hipLaunchKernelGGL(k0w, dim3(1280), dim3(256), 0, stream,
                     WEnc, WTgt, WPtr, Wcb, dec, lhh, tgt, se, xT, hT, tT, sT);
  hipLaunchKernelGGL(k1a_gru, dim3(64), dim3(512), 0, stream,
                     xT, hT, Wih, Whh, bih, bhh, out + Bn*Sn, hnT);
  hipLaunchKernelGGL(k1c_dots, dim3(192), dim3(512), 0, stream,
                     hnT, tT, sT, WEnc, WTgt, WPtr, dEnc, dTgt, c3);
  hipLaunchKernelGGL(k2_gemm, dim3(16, 128), dim3(256), 0, stream,
                     stat, Wcb, dEnc, dTgt, vEnc, vTgt, scE, scT, Aptr);
  hipLaunchKernelGGL(k3_ctx, dim3(128, 2), dim3(1024), 0, stream,
                     scE, scT, stat, ctxG);
  hipLaunchKernelGGL(k3c_c2, dim3(128), dim3(512), 0, stream,
                     ctxG, WPtr, c3, cE, cT);
  hipLaunchKernelGGL(k4_final, dim3(16, 128), dim3(256), 0, stream,
                     Aptr, cE, cT, vPtr, out);
}